// Round 8
// baseline (515.137 us; speedup 1.0000x reference)
//
#include <hip/hip_runtime.h>

#define HW 16384
#define NQ 300
#define NM 100
#define NB 8
#define NC 81
#define KCH 1024   // 16 k-chunks (R6's 32-split regressed: atomics + L2)
#define NKC 16
#define CTP 304    // padded leading dim for transposed cost

typedef __attribute__((ext_vector_type(8))) short frag8;
typedef __attribute__((ext_vector_type(4))) float float4v;
typedef __attribute__((ext_vector_type(4))) unsigned short ushort4v;

__device__ __forceinline__ unsigned short f2bf(float f) {
  union { float f; unsigned u; } c; c.f = f;
  unsigned r = c.u + 0x7FFFu + ((c.u >> 16) & 1u);
  return (unsigned short)(r >> 16);
}

// ---- gm prep: gt_masks (exact 0/1 f32) -> bf16 + row sums ----
__global__ __launch_bounds__(256) void gmprep_kernel(
    const float* __restrict__ gmask, unsigned short* __restrict__ gm,
    float* __restrict__ gsum) {
  int row = blockIdx.x;            // 0..799 = b*NM+m
  int t = threadIdx.x;
  const float4v* src = (const float4v*)(gmask + (size_t)row * HW);
  unsigned short* dst = gm + (size_t)row * HW;
  float s = 0.f;
  for (int i = t; i < HW / 4; i += 256) {
    float4v x = src[i];
    s += (x.x + x.y) + (x.z + x.w);
    ushort4v o = { f2bf(x.x), f2bf(x.y), f2bf(x.z), f2bf(x.w) };
    *(ushort4v*)(dst + i * 4) = o;
  }
  for (int off = 32; off > 0; off >>= 1) s += __shfl_xor(s, off, 64);
  __shared__ float red[4];
  int wave = t >> 6, lane = t & 63;
  if (lane == 0) red[wave] = s;
  __syncthreads();
  if (t == 0) gsum[row] = (red[0] + red[1]) + (red[2] + red[3]);
}

// ---- softmax over 81 classes, one wave per (b,q) row ----
__global__ __launch_bounds__(256) void softmax_kernel(
    const float* __restrict__ logits, float* __restrict__ probs) {
  int wave = threadIdx.x >> 6, lane = threadIdx.x & 63;
  int row = blockIdx.x * 4 + wave;          // < 2400 (grid=600)
  const float* in = logits + (size_t)row * NC;
  float x0 = (lane < NC) ? in[lane] : -1e30f;
  float x1 = (lane + 64 < NC) ? in[lane + 64] : -1e30f;
  float mx = fmaxf(x0, x1);
  for (int off = 32; off > 0; off >>= 1) mx = fmaxf(mx, __shfl_xor(mx, off, 64));
  float e0 = (lane < NC) ? __expf(x0 - mx) : 0.f;
  float e1 = (lane + 64 < NC) ? __expf(x1 - mx) : 0.f;
  float s = e0 + e1;
  for (int off = 32; off > 0; off >>= 1) s += __shfl_xor(s, off, 64);
  float inv = 1.f / s;
  if (lane < NC) probs[(size_t)row * NC + lane] = e0 * inv;
  if (lane + 64 < NC) probs[(size_t)row * NC + lane + 64] = e1 * inv;
}

// ---- fused bf16 MFMA batched GEMM, 4 waves/block over the mt axis ----
// R8: dot was wave-starved (2.4 waves/SIMD; all busy-counters idle; each of
// ~288 loads eats near-full latency). Adding waves via kc (R6) poisoned
// atomics/L2; via in-wave ILP (R7) was neutral (compiler already pipelines).
// This round: 4 waves per block split the SEVEN 16-m tiles {0,1|2,3|4,5|6} —
// 9728 waves (~8/SIMD resident), dotv atomic count UNCHANGED (each cell
// still written once), duplicated A-row reads are same-CU L1/L2 hits.
// Sigmoid divide -> v_rcp_f32 (rel err ~1e-5 << bf16 quant) to keep the
// 4x-duplicated A VALU work cheap. Only wave 0 emits psum.
__global__ __launch_bounds__(256) void dot_kernel(
    const float* __restrict__ pmask, const unsigned short* __restrict__ gm,
    float* __restrict__ dotv, float* __restrict__ psum) {
  int qt = blockIdx.x;                      // 0..18 (16-q tiles)
  int b = blockIdx.y >> 4, kc = blockIdx.y & 15;
  int tid = threadIdx.x;
  int wv = tid >> 6, lane = tid & 63;
  int q0 = qt * 16;
  int row_a = q0 + (lane & 15);
  int ra = (row_a < NQ) ? row_a : NQ - 1;   // clamp; clamped rows never stored
  int koff = (lane >> 4) * 8;
  const float* pA = pmask + ((size_t)b * NQ + ra) * HW + kc * KCH + koff;
  const unsigned short* pB0 = gm + (size_t)b * NM * HW + kc * KCH + koff;
  int mtbase = 2 * wv;                      // wv=3 -> mt 6 only
  int nmt = (wv < 3) ? 2 : 1;
  const unsigned short* pBa;
  const unsigned short* pBb;
  {
    int rb0 = mtbase * 16 + (lane & 15);
    if (rb0 >= NM) rb0 = NM - 1;
    pBa = pB0 + (size_t)rb0 * HW;
    int mt1 = mtbase + 1; if (mt1 > 6) mt1 = 6;
    int rb1 = mt1 * 16 + (lane & 15);
    if (rb1 >= NM) rb1 = NM - 1;
    pBb = pB0 + (size_t)rb1 * HW;
  }
  float4v acc0 = (float4v){0.f, 0.f, 0.f, 0.f};
  float4v acc1 = (float4v){0.f, 0.f, 0.f, 0.f};
  float asum = 0.f;
#pragma unroll 2
  for (int k = 0; k < KCH; k += 32) {
    float4v x0 = *(const float4v*)(pA + k);
    float4v x1 = *(const float4v*)(pA + k + 4);
    float s0 = __builtin_amdgcn_rcpf(1.f + __expf(-x0.x));
    float s1 = __builtin_amdgcn_rcpf(1.f + __expf(-x0.y));
    float s2 = __builtin_amdgcn_rcpf(1.f + __expf(-x0.z));
    float s3 = __builtin_amdgcn_rcpf(1.f + __expf(-x0.w));
    float s4 = __builtin_amdgcn_rcpf(1.f + __expf(-x1.x));
    float s5 = __builtin_amdgcn_rcpf(1.f + __expf(-x1.y));
    float s6 = __builtin_amdgcn_rcpf(1.f + __expf(-x1.z));
    float s7 = __builtin_amdgcn_rcpf(1.f + __expf(-x1.w));
    asum += ((s0 + s1) + (s2 + s3)) + ((s4 + s5) + (s6 + s7));
    frag8 a;
    a[0] = (short)f2bf(s0); a[1] = (short)f2bf(s1);
    a[2] = (short)f2bf(s2); a[3] = (short)f2bf(s3);
    a[4] = (short)f2bf(s4); a[5] = (short)f2bf(s5);
    a[6] = (short)f2bf(s6); a[7] = (short)f2bf(s7);
    frag8 b0 = *(const frag8*)(pBa + k);
    acc0 = __builtin_amdgcn_mfma_f32_16x16x32_bf16(a, b0, acc0, 0, 0, 0);
    if (nmt > 1) {                       // wave-uniform branch
      frag8 b1 = *(const frag8*)(pBb + k);
      acc1 = __builtin_amdgcn_mfma_f32_16x16x32_bf16(a, b1, acc1, 0, 0, 0);
    }
  }
  // psum: computed identically in all 4 waves; wave 0 alone emits.
  // lanes l, l+16, l+32, l+48 share row_a -> 4-lane pre-reduce, 1 atomic.
  if (wv == 0) {
    asum += __shfl_xor(asum, 16, 64);
    asum += __shfl_xor(asum, 32, 64);
    if (lane < 16 && row_a < NQ) unsafeAtomicAdd(&psum[b * NQ + row_a], asum);
  }
  // C/D layout: col = lane&15 (m), row = (lane>>4)*4 + r (q)
  {
    int cm = mtbase * 16 + (lane & 15);
    if (cm < NM) {
#pragma unroll
      for (int r = 0; r < 4; ++r) {
        int cq = q0 + (lane >> 4) * 4 + r;
        if (cq < NQ)
          unsafeAtomicAdd(&dotv[((size_t)b * NQ + cq) * NM + cm], acc0[r]);
      }
    }
  }
  if (nmt > 1) {
    int cm = (mtbase + 1) * 16 + (lane & 15);
    if (cm < NM) {
#pragma unroll
      for (int r = 0; r < 4; ++r) {
        int cq = q0 + (lane >> 4) * 4 + r;
        if (cq < NQ)
          unsafeAtomicAdd(&dotv[((size_t)b * NQ + cq) * NM + cm], acc1[r]);
      }
    }
  }
}

// ---- combine all cost terms -> C (d_out) and transposed copy CT (ws) ----
__global__ __launch_bounds__(256) void combine_kernel(
    const float* __restrict__ dotv, const float* __restrict__ psum,
    const float* __restrict__ gsum, const float* __restrict__ probs,
    const int* __restrict__ labels, const float* __restrict__ pboxes,
    const float* __restrict__ gboxes, float* __restrict__ outC,
    float* __restrict__ ct) {
  int idx = blockIdx.x * 256 + threadIdx.x;
  if (idx >= NB * NQ * NM) return;
  int b = idx / (NQ * NM);
  int r = idx - b * (NQ * NM);
  int q = r / NM;
  int m = r - q * NM;
  float num = 2.f * dotv[idx];
  float den = psum[b * NQ + q] + gsum[b * NM + m];
  float cmask = 1.f - num / (den + 1e-6f);
  int lab = labels[b * NM + m];
  float cclass = -probs[((size_t)b * NQ + q) * NC + lab];
  const float* pb = pboxes + ((size_t)b * NQ + q) * 4;
  const float* gb = gboxes + ((size_t)b * NM + m) * 4;
  float p0 = pb[0], p1 = pb[1], p2 = pb[2], p3 = pb[3];
  float g0 = gb[0], g1 = gb[1], g2 = gb[2], g3 = gb[3];
  float cbbox = fabsf(p0 - g0) + fabsf(p1 - g1) + fabsf(p2 - g2) + fabsf(p3 - g3);
  float iw = fmaxf(fminf(p2, g2) - fmaxf(p0, g0), 0.f);
  float ih = fmaxf(fminf(p3, g3) - fmaxf(p1, g1), 0.f);
  float inter = iw * ih;
  float a1 = (p2 - p0) * (p3 - p1), a2 = (g2 - g0) * (g3 - g1);
  float uni = a1 + a2 - inter;
  float iou = inter / (uni + 1e-6f);
  float aw = fmaxf(fmaxf(p2, g2) - fminf(p0, g0), 0.f);
  float ah = fmaxf(fmaxf(p3, g3) - fminf(p1, g1), 0.f);
  float am = aw * ah;
  float giou = iou - (am - uni) / (am + 1e-6f);
  float C = cclass + 5.f * (cbbox - giou) + 2.f * cmask;
  outC[idx] = C;
  ct[((size_t)b * NM + m) * CTP + q] = C;   // transposed for the solver
}

// f32 full-wave min via DPP (row_shr 1/2/4/8 + bcast15/31 -> lane 63),
// broadcast back through an SGPR. ~6 dependent VALU ops + 1 readlane.
__device__ __forceinline__ float wave_fmin_bcast(float x) {
  int t;
  t = __builtin_amdgcn_update_dpp(__float_as_int(x), __float_as_int(x), 0x111, 0xf, 0xf, false);
  x = fminf(x, __int_as_float(t));  // row_shr:1
  t = __builtin_amdgcn_update_dpp(__float_as_int(x), __float_as_int(x), 0x112, 0xf, 0xf, false);
  x = fminf(x, __int_as_float(t));  // row_shr:2
  t = __builtin_amdgcn_update_dpp(__float_as_int(x), __float_as_int(x), 0x114, 0xf, 0xf, false);
  x = fminf(x, __int_as_float(t));  // row_shr:4
  t = __builtin_amdgcn_update_dpp(__float_as_int(x), __float_as_int(x), 0x118, 0xf, 0xf, false);
  x = fminf(x, __int_as_float(t));  // row_shr:8
  t = __builtin_amdgcn_update_dpp(__float_as_int(x), __float_as_int(x), 0x142, 0xf, 0xf, false);
  x = fminf(x, __int_as_float(t));  // row_bcast:15
  t = __builtin_amdgcn_update_dpp(__float_as_int(x), __float_as_int(x), 0x143, 0xf, 0xf, false);
  x = fminf(x, __int_as_float(t));  // row_bcast:31
  return __int_as_float(__builtin_amdgcn_readlane(__float_as_int(x), 63));
}

// ---- Jonker-Volgenant on cost.T [100 x 300], one wave per batch ----
// EXACT v3 (R2 kernel, measured 127.8us, passed): greedy init + budgeted
// ARR + Dijkstra-form SAP with p/u register mirrors and DPP reduces.
extern __shared__ char hsmem[];
__global__ __launch_bounds__(64) void hungarian_kernel(
    const float* __restrict__ ct, float* __restrict__ out) {
  float* cost   = (float*)hsmem;                     // 100*304 f32 = 121600 B
  float* u      = (float*)(hsmem + 121600);          // 100 f32
  int*   p      = (int*)(hsmem + 122000);            // 320 int (col -> row)
  int*   way    = (int*)(hsmem + 123280);            // 320 int
  int*   colOwn = (int*)(hsmem + 124560);            // 320 int (reused: flist)
  int*   queue  = (int*)(hsmem + 125840);            // 400 int
  int*   qmisc  = (int*)(hsmem + 127440);            // 8 int: [0]=head [1]=tail
  int*   flist  = colOwn;                            // free-row list (<=100)
  const int b = blockIdx.x;
  const int lane = threadIdx.x;
  const float INF = __builtin_inff();

  // vectorized cost load: 121600 B as float4 (CTP=304 keeps rows 16B-aligned)
  {
    const float4v* a4 = (const float4v*)(ct + (size_t)b * NM * CTP);
    float4v* c4 = (float4v*)cost;
    for (int i = lane; i < NM * CTP / 4; i += 64) c4[i] = a4[i];
  }
#pragma unroll
  for (int w = 0; w < 5; ++w) {
    p[lane + 64 * w] = -1;
    colOwn[lane + 64 * w] = 0x7fffffff;
  }
  if (lane == 0) { qmisc[0] = 0; qmisc[1] = 0; }
  float v[5];
#pragma unroll
  for (int w = 0; w < 5; ++w) v[w] = 0.f;
  __syncthreads();

  // ---- row reduction: u[i] = min_j cost[i][j], colA = first argmin col ----
  int rarg0 = 0, rarg1 = 0;
  {
    int i = lane;                 // rows 0..63
    float mv = INF; int cj = 0;
    for (int j = 0; j < NQ; ++j) {
      float c = cost[i * CTP + j];
      if (c < mv) { mv = c; cj = j; }
    }
    u[i] = mv; rarg0 = cj;
  }
  if (lane < NM - 64) {           // rows 64..99
    int i = lane + 64;
    float mv = INF; int cj = 0;
    for (int j = 0; j < NQ; ++j) {
      float c = cost[i * CTP + j];
      if (c < mv) { mv = c; cj = j; }
    }
    u[i] = mv; rarg1 = cj;
  }
  // ---- parallel greedy: lowest row index wins its argmin column ----
  atomicMin(&colOwn[rarg0], lane);
  if (lane < NM - 64) atomicMin(&colOwn[rarg1], lane + 64);
  __syncthreads();
  int free0 = 0, free1 = 0;
  {
    bool won = (colOwn[rarg0] == lane);
    if (won) p[rarg0] = lane;
    free0 = won ? 0 : 1;
  }
  int rowUsed0 = free0 ? 0 : 1;
  int rowUsed1 = 0;
  if (lane < NM - 64) {
    bool won = (colOwn[rarg1] == lane + 64);
    if (won) p[rarg1] = lane + 64;
    rowUsed1 = won ? 1 : 0;
    free1 = won ? 0 : 1;
  }
  __shared__ int rowUsedA[NM];
  rowUsedA[lane < NM ? lane : 0] = 0;
  rowUsedA[lane] = rowUsed0;
  if (lane < NM - 64) rowUsedA[lane + 64] = rowUsed1;
  // deterministic free-row queue, ascending row index
  {
    unsigned long long m0 = __ballot(free0 != 0);
    if (free0) queue[__popcll(m0 & ((1ull << lane) - 1ull))] = lane;
    int base = (int)__popcll(m0);
    unsigned long long m1 = __ballot(free1 != 0);
    if (free1) queue[base + (int)__popcll(m1 & ((1ull << lane) - 1ull))] = lane + 64;
    base += (int)__popcll(m1);
    if (lane == 0) qmisc[1] = base;
  }

  // ---- augmenting row reduction (budgeted) ----
  int pops = 0;
  while (true) {
    __syncthreads();
    int h = qmisc[0], t = qmisc[1];
    if (h >= t || pops >= 192) break;
    int i = queue[h];
    ++pops;
    if (lane == 0) qmisc[0] = h + 1;
    // wave-parallel scan: keep per-w reduced costs + per-lane min1/min2
    float tv[5];
    float m1 = INF, m2 = INF;
#pragma unroll
    for (int w = 0; w < 5; ++w) {
      int j = lane + 64 * w;
      float tt = (j < NQ) ? (cost[i * CTP + j] - v[w]) : INF;
      tv[w] = tt;
      if (tt < m1) { m2 = m1; m1 = tt; } else if (tt < m2) m2 = tt;
    }
    float m1g = wave_fmin_bcast(m1);
    int j1 = -1;
#pragma unroll
    for (int w = 0; w < 5; ++w) {
      unsigned long long mk = __ballot(tv[w] == m1g);
      if (j1 < 0 && mk) j1 = (int)__builtin_ctzll(mk) + 64 * w;
    }
    // global 2nd min = min over all cols except j1
    float c2c = INF;
#pragma unroll
    for (int w = 0; w < 5; ++w)
      if (lane + 64 * w != j1) c2c = fminf(c2c, tv[w]);
    float c2 = wave_fmin_bcast(c2c);
    float delta = (c2 > m1g) ? (c2 - m1g) : 0.f;
    int i1 = p[j1];
    if (i1 >= 0 && delta <= 0.f) {
      // exact tie on an occupied column: leave row i free for SAP
      if (lane == 0) u[i] = c2;
      continue;
    }
#pragma unroll
    for (int w = 0; w < 5; ++w) if (lane + 64 * w == j1) v[w] -= delta;
    if (lane == 0) {
      u[i] = c2;
      p[j1] = i;
      rowUsedA[i] = 1;
      if (i1 >= 0) { rowUsedA[i1] = 0; queue[t] = i1; qmisc[1] = t + 1; }
    }
  }
  __syncthreads();

  // ---- collect free rows once (SAP never frees an assigned row) ----
  int nfree;
  {
    int r0 = rowUsedA[lane];
    int r1 = (lane < NM - 64) ? rowUsedA[lane + 64] : 1;
    unsigned long long m0 = __ballot(r0 == 0);
    if (!r0) flist[__popcll(m0 & ((1ull << lane) - 1ull))] = lane;
    int base = (int)__popcll(m0);
    unsigned long long m1 = __ballot(r1 == 0);
    if (!r1) flist[base + (int)__popcll(m1 & ((1ull << lane) - 1ull))] = lane + 64;
    nfree = base + (int)__popcll(m1);
  }
  __syncthreads();

  // register mirrors of p[] and u[] (valid while frozen within a SAP phase)
  int pr0, pr1, pr2, pr3, pr4;
  float ur0, ur1;
  pr0 = p[lane]; pr1 = p[lane + 64]; pr2 = p[lane + 128];
  pr3 = p[lane + 192]; pr4 = p[lane + 256];
  ur0 = u[lane];
  ur1 = (lane < NM - 64) ? u[lane + 64] : 0.f;

  // ---- shortest augmenting path (Dijkstra form) for leftover free rows ----
  for (int fi = 0; fi < nfree; ++fi) {
    int i = flist[fi];
    float dv[5]; int usedR[5];
#pragma unroll
    for (int w = 0; w < 5; ++w) {
      int j = lane + 64 * w;
      dv[w] = INF;
      usedR[w] = (j >= NQ) ? 1 : 0;
      way[j] = -1;
    }
    float S = 0.f;
    int nr = i, j0 = -1;
    while (true) {
      float urow;
      {
        int bits = (nr < 64)
            ? __builtin_amdgcn_readlane(__float_as_int(ur0), nr & 63)
            : __builtin_amdgcn_readlane(__float_as_int(ur1), nr & 63);
        urow = __int_as_float(bits);
      }
      int base = nr * CTP;
      float c0 = cost[base + lane];
      float c1 = cost[base + lane + 64];
      float c2_ = cost[base + lane + 128];
      float c3 = cost[base + lane + 192];
      float c4 = cost[base + lane + 256];   // j>=300 lanes: discarded (usedR)
      float cr[5] = {c0, c1, c2_, c3, c4};
      float cmin = INF;
#pragma unroll
      for (int w = 0; w < 5; ++w) {
        if (!usedR[w]) {
          float cand = S + cr[w] - urow - v[w];
          if (cand < dv[w]) { dv[w] = cand; way[lane + 64 * w] = j0; }
          cmin = fminf(cmin, dv[w]);
        }
      }
      float m = wave_fmin_bcast(cmin);
      int j1 = -1;
#pragma unroll
      for (int w = 0; w < 5; ++w) {
        unsigned long long mk = __ballot(!usedR[w] && dv[w] == m);
        if (j1 < 0 && mk) j1 = (int)__builtin_ctzll(mk) + 64 * w;
      }
      S = m;
#pragma unroll
      for (int w = 0; w < 5; ++w) if (lane + 64 * w == j1) usedR[w] = 1;
      j0 = j1;
      // p[j1] via readlane from mirror (uniform j1; p frozen in-phase)
      int nr2;
      {
        int sl = j1 >> 6, ln = j1 & 63;
        if (sl == 0)      nr2 = __builtin_amdgcn_readlane(pr0, ln);
        else if (sl == 1) nr2 = __builtin_amdgcn_readlane(pr1, ln);
        else if (sl == 2) nr2 = __builtin_amdgcn_readlane(pr2, ln);
        else if (sl == 3) nr2 = __builtin_amdgcn_readlane(pr3, ln);
        else              nr2 = __builtin_amdgcn_readlane(pr4, ln);
      }
      if (nr2 < 0) break;
      nr = nr2;
    }
    // phase-end dual updates (mirror pr* is pre-augmentation p — required)
#pragma unroll
    for (int w = 0; w < 5; ++w) {
      int j = lane + 64 * w;
      if (j < NQ && usedR[w]) {
        float amt = S - dv[w];            // = sum of deltas since j joined
        v[w] -= amt;
        int pj = (w == 0) ? pr0 : (w == 1) ? pr1 : (w == 2) ? pr2
               : (w == 3) ? pr3 : pr4;
        if (pj >= 0) u[pj] += amt;        // distinct rows across lanes
      }
    }
    if (lane == 0) u[i] += S;
    __syncthreads();
    if (lane == 0) {                      // backtrack augmenting path
      int j = j0;
      while (j != -1) {
        int jp = way[j];
        p[j] = (jp != -1) ? p[jp] : i;
        j = jp;
      }
    }
    __syncthreads();
    // refresh mirrors (p rewired by backtrack, u updated above)
    pr0 = p[lane]; pr1 = p[lane + 64]; pr2 = p[lane + 128];
    pr3 = p[lane + 192]; pr4 = p[lane + 256];
    ur0 = u[lane];
    ur1 = (lane < NM - 64) ? u[lane + 64] : 0.f;
  }

  // ---- parallel emit: sorted (pred, gt) pairs via ballot prefix ----
  {
    float* po = out + NB * NQ * NM + b * NM;
    float* go = out + NB * NQ * NM + NB * NM + b * NM;
    int base = 0;
    int prw[5] = {pr0, pr1, pr2, pr3, pr4};
#pragma unroll
    for (int w = 0; w < 5; ++w) {
      int j = lane + 64 * w;
      int pj = (j < NQ) ? prw[w] : -1;
      unsigned long long mask = __ballot(pj >= 0);
      if (pj >= 0) {
        int pos = base + (int)__popcll(mask & ((1ull << lane) - 1ull));
        po[pos] = (float)j;
        go[pos] = (float)pj;
      }
      base += (int)__popcll(mask);
    }
  }
}

extern "C" void kernel_launch(void* const* d_in, const int* in_sizes, int n_in,
                              void* d_out, int out_size, void* d_ws, size_t ws_size,
                              hipStream_t stream) {
  const float* logits = (const float*)d_in[0];
  const float* pboxes = (const float*)d_in[1];
  const float* pmask  = (const float*)d_in[2];
  const int*   labels = (const int*)d_in[3];
  const float* gboxes = (const float*)d_in[4];
  const float* gmask  = (const float*)d_in[5];
  float* out = (float*)d_out;
  char* ws = (char*)d_ws;

  // ws layout (bytes) — pm staging eliminated
  unsigned short* gmb  = (unsigned short*)(ws + 0);          //  26,214,400
  float* dotv  = (float*)(ws + 26214400);                    //     960,000
  float* psum  = (float*)(ws + 27174400);                    //       9,600  (contiguous after dotv)
  float* gsum  = (float*)(ws + 27184000);                    //       3,200
  float* probs = (float*)(ws + 27187200);                    //     777,600
  float* ct    = (float*)(ws + 27964800);                    //     972,800

  hipFuncSetAttribute(reinterpret_cast<const void*>(hungarian_kernel),
                      hipFuncAttributeMaxDynamicSharedMemorySize, 127472);

  // zero dotv + psum in one memset (contiguous)
  hipMemsetAsync(dotv, 0, NB * NQ * NM * sizeof(float) + NB * NQ * sizeof(float), stream);
  hipLaunchKernelGGL(gmprep_kernel, dim3(NB * NM), dim3(256), 0, stream,
                     gmask, gmb, gsum);
  hipLaunchKernelGGL(softmax_kernel, dim3(600), dim3(256), 0, stream, logits, probs);
  hipLaunchKernelGGL(dot_kernel, dim3(19, NB * NKC), dim3(256), 0, stream,
                     pmask, gmb, dotv, psum);
  hipLaunchKernelGGL(combine_kernel, dim3((NB * NQ * NM + 255) / 256), dim3(256), 0, stream,
                     dotv, psum, gsum, probs, labels, pboxes, gboxes, out, ct);
  hipLaunchKernelGGL(hungarian_kernel, dim3(NB), dim3(64), 127472, stream, ct, out);
}

// Round 9
// 464.070 us; speedup vs baseline: 1.1100x; 1.1100x over previous
//
#include <hip/hip_runtime.h>

#define HW 16384
#define NQ 300
#define NM 100
#define NB 8
#define NC 81
#define KCH 1024   // 16 k-chunks (R6 32-split regressed: atomics + L2 reuse)
#define NKC 16
#define CTP 304    // padded leading dim for transposed cost

typedef __attribute__((ext_vector_type(8))) short frag8;
typedef __attribute__((ext_vector_type(4))) float float4v;
typedef __attribute__((ext_vector_type(4))) unsigned short ushort4v;

__device__ __forceinline__ unsigned short f2bf(float f) {
  union { float f; unsigned u; } c; c.f = f;
  unsigned r = c.u + 0x7FFFu + ((c.u >> 16) & 1u);
  return (unsigned short)(r >> 16);
}

// ---- fused prep: [0,800) gm->bf16+gsum | [800,1400) softmax | [1400,1460) zero ----
// R9: one dispatch replaces gmprep + softmax + hipMemsetAsync (dispatch-path
// theory: ~170us of the total is serialized launch overhead; 7 -> 4 dispatches).
__global__ __launch_bounds__(256) void prep2_kernel(
    const float* __restrict__ gmask, unsigned short* __restrict__ gm,
    float* __restrict__ gsum, const float* __restrict__ logits,
    float* __restrict__ probs, float* __restrict__ zero_base) {
  int blk = blockIdx.x;
  int t = threadIdx.x;
  if (blk < NB * NM) {
    // gm prep: gt_masks (exact 0/1 f32) -> bf16 + row sums
    int row = blk;
    const float4v* src = (const float4v*)(gmask + (size_t)row * HW);
    unsigned short* dst = gm + (size_t)row * HW;
    float s = 0.f;
    for (int i = t; i < HW / 4; i += 256) {
      float4v x = src[i];
      s += (x.x + x.y) + (x.z + x.w);
      ushort4v o = { f2bf(x.x), f2bf(x.y), f2bf(x.z), f2bf(x.w) };
      *(ushort4v*)(dst + i * 4) = o;
    }
    for (int off = 32; off > 0; off >>= 1) s += __shfl_xor(s, off, 64);
    __shared__ float red[4];
    int wave = t >> 6, lane = t & 63;
    if (lane == 0) red[wave] = s;
    __syncthreads();
    if (t == 0) gsum[row] = (red[0] + red[1]) + (red[2] + red[3]);
  } else if (blk < NB * NM + 600) {
    // softmax over 81 classes, one wave per (b,q) row
    int wave = t >> 6, lane = t & 63;
    int row = (blk - NB * NM) * 4 + wave;   // < 2400
    const float* in = logits + (size_t)row * NC;
    float x0 = (lane < NC) ? in[lane] : -1e30f;
    float x1 = (lane + 64 < NC) ? in[lane + 64] : -1e30f;
    float mx = fmaxf(x0, x1);
    for (int off = 32; off > 0; off >>= 1) mx = fmaxf(mx, __shfl_xor(mx, off, 64));
    float e0 = (lane < NC) ? __expf(x0 - mx) : 0.f;
    float e1 = (lane + 64 < NC) ? __expf(x1 - mx) : 0.f;
    float s = e0 + e1;
    for (int off = 32; off > 0; off >>= 1) s += __shfl_xor(s, off, 64);
    float inv = 1.f / s;
    if (lane < NC) probs[(size_t)row * NC + lane] = e0 * inv;
    if (lane + 64 < NC) probs[(size_t)row * NC + lane + 64] = e1 * inv;
  } else {
    // zero dotv (240000 f32) + psum (2400 f32), contiguous = 60600 float4
    float4v* z = (float4v*)zero_base;
    float4v zv = (float4v){0.f, 0.f, 0.f, 0.f};
    for (int i = (blk - (NB * NM + 600)) * 256 + t; i < 60600; i += 60 * 256)
      z[i] = zv;
  }
}

// ---- fused bf16 MFMA batched GEMM (EXACT R5 form, measured 130us):
//      sigmoid(pmask f32) inline -> bf16 A, dot via fp32 atomics,
//      psum via one atomic per 4 lanes. One wave per (qt,b,kc). ----
// R6 (kc x2): FETCH +16MB, atomics x2 -> 183us. R7 (reg ping-pong): neutral
// (compiler already pipelines). R8 (4-wave mt-split): FETCH +81MB (A dup
// missed L1/L2) -> 174us. BW pinned ~1.7TB/s across 19-65% occupancy ->
// shared-resource cap for the 16x128B scattered pattern; R5 form is the
// best-measured point of this structure.
__global__ __launch_bounds__(64) void dot_kernel(
    const float* __restrict__ pmask, const unsigned short* __restrict__ gm,
    float* __restrict__ dotv, float* __restrict__ psum) {
  int qt = blockIdx.x;                      // 0..18 (16-q tiles)
  int b = blockIdx.y >> 4, kc = blockIdx.y & 15;
  int lane = threadIdx.x;
  int q0 = qt * 16;
  int row_a = q0 + (lane & 15);
  int ra = (row_a < NQ) ? row_a : NQ - 1;   // clamp; clamped rows never stored
  int koff = (lane >> 4) * 8;
  const float* pA = pmask + ((size_t)b * NQ + ra) * HW + kc * KCH + koff;
  const unsigned short* pB0 = gm + (size_t)b * NM * HW + kc * KCH + koff;
  const unsigned short* pB[7];
#pragma unroll
  for (int mt = 0; mt < 7; ++mt) {
    int row_b = mt * 16 + (lane & 15);
    int rb = (row_b < NM) ? row_b : NM - 1;
    pB[mt] = pB0 + (size_t)rb * HW;
  }
  float4v acc[7];
#pragma unroll
  for (int mt = 0; mt < 7; ++mt) acc[mt] = (float4v){0.f, 0.f, 0.f, 0.f};
  float asum = 0.f;
#pragma unroll 2
  for (int k = 0; k < KCH; k += 32) {
    float4v x0 = *(const float4v*)(pA + k);
    float4v x1 = *(const float4v*)(pA + k + 4);
    float s0 = 1.f / (1.f + __expf(-x0.x));
    float s1 = 1.f / (1.f + __expf(-x0.y));
    float s2 = 1.f / (1.f + __expf(-x0.z));
    float s3 = 1.f / (1.f + __expf(-x0.w));
    float s4 = 1.f / (1.f + __expf(-x1.x));
    float s5 = 1.f / (1.f + __expf(-x1.y));
    float s6 = 1.f / (1.f + __expf(-x1.z));
    float s7 = 1.f / (1.f + __expf(-x1.w));
    asum += ((s0 + s1) + (s2 + s3)) + ((s4 + s5) + (s6 + s7));
    frag8 a;
    a[0] = (short)f2bf(s0); a[1] = (short)f2bf(s1);
    a[2] = (short)f2bf(s2); a[3] = (short)f2bf(s3);
    a[4] = (short)f2bf(s4); a[5] = (short)f2bf(s5);
    a[6] = (short)f2bf(s6); a[7] = (short)f2bf(s7);
#pragma unroll
    for (int mt = 0; mt < 7; ++mt) {
      frag8 bb = *(const frag8*)(pB[mt] + k);
      acc[mt] = __builtin_amdgcn_mfma_f32_16x16x32_bf16(a, bb, acc[mt], 0, 0, 0);
    }
  }
  asum += __shfl_xor(asum, 16, 64);
  asum += __shfl_xor(asum, 32, 64);
  if (lane < 16 && row_a < NQ) unsafeAtomicAdd(&psum[b * NQ + row_a], asum);
  // C/D layout: col = lane&15 (m), row = (lane>>4)*4 + r (q)
#pragma unroll
  for (int mt = 0; mt < 7; ++mt) {
    int cm = mt * 16 + (lane & 15);
    if (cm < NM) {
#pragma unroll
      for (int r = 0; r < 4; ++r) {
        int cq = q0 + (lane >> 4) * 4 + r;
        if (cq < NQ)
          unsafeAtomicAdd(&dotv[((size_t)b * NQ + cq) * NM + cm], acc[mt][r]);
      }
    }
  }
}

// ---- combine all cost terms -> C (d_out) and transposed copy CT (ws) ----
__global__ __launch_bounds__(256) void combine_kernel(
    const float* __restrict__ dotv, const float* __restrict__ psum,
    const float* __restrict__ gsum, const float* __restrict__ probs,
    const int* __restrict__ labels, const float* __restrict__ pboxes,
    const float* __restrict__ gboxes, float* __restrict__ outC,
    float* __restrict__ ct) {
  int idx = blockIdx.x * 256 + threadIdx.x;
  if (idx >= NB * NQ * NM) return;
  int b = idx / (NQ * NM);
  int r = idx - b * (NQ * NM);
  int q = r / NM;
  int m = r - q * NM;
  float num = 2.f * dotv[idx];
  float den = psum[b * NQ + q] + gsum[b * NM + m];
  float cmask = 1.f - num / (den + 1e-6f);
  int lab = labels[b * NM + m];
  float cclass = -probs[((size_t)b * NQ + q) * NC + lab];
  const float* pb = pboxes + ((size_t)b * NQ + q) * 4;
  const float* gb = gboxes + ((size_t)b * NM + m) * 4;
  float p0 = pb[0], p1 = pb[1], p2 = pb[2], p3 = pb[3];
  float g0 = gb[0], g1 = gb[1], g2 = gb[2], g3 = gb[3];
  float cbbox = fabsf(p0 - g0) + fabsf(p1 - g1) + fabsf(p2 - g2) + fabsf(p3 - g3);
  float iw = fmaxf(fminf(p2, g2) - fmaxf(p0, g0), 0.f);
  float ih = fmaxf(fminf(p3, g3) - fmaxf(p1, g1), 0.f);
  float inter = iw * ih;
  float a1 = (p2 - p0) * (p3 - p1), a2 = (g2 - g0) * (g3 - g1);
  float uni = a1 + a2 - inter;
  float iou = inter / (uni + 1e-6f);
  float aw = fmaxf(fmaxf(p2, g2) - fminf(p0, g0), 0.f);
  float ah = fmaxf(fmaxf(p3, g3) - fminf(p1, g1), 0.f);
  float am = aw * ah;
  float giou = iou - (am - uni) / (am + 1e-6f);
  float C = cclass + 5.f * (cbbox - giou) + 2.f * cmask;
  outC[idx] = C;
  ct[((size_t)b * NM + m) * CTP + q] = C;   // transposed for the solver
}

// f32 full-wave min via DPP (row_shr 1/2/4/8 + bcast15/31 -> lane 63),
// broadcast back through an SGPR. ~6 dependent VALU ops + 1 readlane.
__device__ __forceinline__ float wave_fmin_bcast(float x) {
  int t;
  t = __builtin_amdgcn_update_dpp(__float_as_int(x), __float_as_int(x), 0x111, 0xf, 0xf, false);
  x = fminf(x, __int_as_float(t));  // row_shr:1
  t = __builtin_amdgcn_update_dpp(__float_as_int(x), __float_as_int(x), 0x112, 0xf, 0xf, false);
  x = fminf(x, __int_as_float(t));  // row_shr:2
  t = __builtin_amdgcn_update_dpp(__float_as_int(x), __float_as_int(x), 0x114, 0xf, 0xf, false);
  x = fminf(x, __int_as_float(t));  // row_shr:4
  t = __builtin_amdgcn_update_dpp(__float_as_int(x), __float_as_int(x), 0x118, 0xf, 0xf, false);
  x = fminf(x, __int_as_float(t));  // row_shr:8
  t = __builtin_amdgcn_update_dpp(__float_as_int(x), __float_as_int(x), 0x142, 0xf, 0xf, false);
  x = fminf(x, __int_as_float(t));  // row_bcast:15
  t = __builtin_amdgcn_update_dpp(__float_as_int(x), __float_as_int(x), 0x143, 0xf, 0xf, false);
  x = fminf(x, __int_as_float(t));  // row_bcast:31
  return __int_as_float(__builtin_amdgcn_readlane(__float_as_int(x), 63));
}

// ---- Jonker-Volgenant on cost.T [100 x 300], one wave per batch ----
// EXACT v3 (R2 kernel, measured 127.8us, passed): greedy init + budgeted
// ARR + Dijkstra-form SAP with p/u register mirrors and DPP reduces.
extern __shared__ char hsmem[];
__global__ __launch_bounds__(64) void hungarian_kernel(
    const float* __restrict__ ct, float* __restrict__ out) {
  float* cost   = (float*)hsmem;                     // 100*304 f32 = 121600 B
  float* u      = (float*)(hsmem + 121600);          // 100 f32
  int*   p      = (int*)(hsmem + 122000);            // 320 int (col -> row)
  int*   way    = (int*)(hsmem + 123280);            // 320 int
  int*   colOwn = (int*)(hsmem + 124560);            // 320 int (reused: flist)
  int*   queue  = (int*)(hsmem + 125840);            // 400 int
  int*   qmisc  = (int*)(hsmem + 127440);            // 8 int: [0]=head [1]=tail
  int*   flist  = colOwn;                            // free-row list (<=100)
  const int b = blockIdx.x;
  const int lane = threadIdx.x;
  const float INF = __builtin_inff();

  // vectorized cost load: 121600 B as float4 (CTP=304 keeps rows 16B-aligned)
  {
    const float4v* a4 = (const float4v*)(ct + (size_t)b * NM * CTP);
    float4v* c4 = (float4v*)cost;
    for (int i = lane; i < NM * CTP / 4; i += 64) c4[i] = a4[i];
  }
#pragma unroll
  for (int w = 0; w < 5; ++w) {
    p[lane + 64 * w] = -1;
    colOwn[lane + 64 * w] = 0x7fffffff;
  }
  if (lane == 0) { qmisc[0] = 0; qmisc[1] = 0; }
  float v[5];
#pragma unroll
  for (int w = 0; w < 5; ++w) v[w] = 0.f;
  __syncthreads();

  // ---- row reduction: u[i] = min_j cost[i][j], colA = first argmin col ----
  int rarg0 = 0, rarg1 = 0;
  {
    int i = lane;                 // rows 0..63
    float mv = INF; int cj = 0;
    for (int j = 0; j < NQ; ++j) {
      float c = cost[i * CTP + j];
      if (c < mv) { mv = c; cj = j; }
    }
    u[i] = mv; rarg0 = cj;
  }
  if (lane < NM - 64) {           // rows 64..99
    int i = lane + 64;
    float mv = INF; int cj = 0;
    for (int j = 0; j < NQ; ++j) {
      float c = cost[i * CTP + j];
      if (c < mv) { mv = c; cj = j; }
    }
    u[i] = mv; rarg1 = cj;
  }
  // ---- parallel greedy: lowest row index wins its argmin column ----
  atomicMin(&colOwn[rarg0], lane);
  if (lane < NM - 64) atomicMin(&colOwn[rarg1], lane + 64);
  __syncthreads();
  int free0 = 0, free1 = 0;
  {
    bool won = (colOwn[rarg0] == lane);
    if (won) p[rarg0] = lane;
    free0 = won ? 0 : 1;
  }
  int rowUsed0 = free0 ? 0 : 1;
  int rowUsed1 = 0;
  if (lane < NM - 64) {
    bool won = (colOwn[rarg1] == lane + 64);
    if (won) p[rarg1] = lane + 64;
    rowUsed1 = won ? 1 : 0;
    free1 = won ? 0 : 1;
  }
  __shared__ int rowUsedA[NM];
  rowUsedA[lane < NM ? lane : 0] = 0;
  rowUsedA[lane] = rowUsed0;
  if (lane < NM - 64) rowUsedA[lane + 64] = rowUsed1;
  // deterministic free-row queue, ascending row index
  {
    unsigned long long m0 = __ballot(free0 != 0);
    if (free0) queue[__popcll(m0 & ((1ull << lane) - 1ull))] = lane;
    int base = (int)__popcll(m0);
    unsigned long long m1 = __ballot(free1 != 0);
    if (free1) queue[base + (int)__popcll(m1 & ((1ull << lane) - 1ull))] = lane + 64;
    base += (int)__popcll(m1);
    if (lane == 0) qmisc[1] = base;
  }

  // ---- augmenting row reduction (budgeted) ----
  int pops = 0;
  while (true) {
    __syncthreads();
    int h = qmisc[0], t = qmisc[1];
    if (h >= t || pops >= 192) break;
    int i = queue[h];
    ++pops;
    if (lane == 0) qmisc[0] = h + 1;
    // wave-parallel scan: keep per-w reduced costs + per-lane min1/min2
    float tv[5];
    float m1 = INF, m2 = INF;
#pragma unroll
    for (int w = 0; w < 5; ++w) {
      int j = lane + 64 * w;
      float tt = (j < NQ) ? (cost[i * CTP + j] - v[w]) : INF;
      tv[w] = tt;
      if (tt < m1) { m2 = m1; m1 = tt; } else if (tt < m2) m2 = tt;
    }
    float m1g = wave_fmin_bcast(m1);
    int j1 = -1;
#pragma unroll
    for (int w = 0; w < 5; ++w) {
      unsigned long long mk = __ballot(tv[w] == m1g);
      if (j1 < 0 && mk) j1 = (int)__builtin_ctzll(mk) + 64 * w;
    }
    // global 2nd min = min over all cols except j1
    float c2c = INF;
#pragma unroll
    for (int w = 0; w < 5; ++w)
      if (lane + 64 * w != j1) c2c = fminf(c2c, tv[w]);
    float c2 = wave_fmin_bcast(c2c);
    float delta = (c2 > m1g) ? (c2 - m1g) : 0.f;
    int i1 = p[j1];
    if (i1 >= 0 && delta <= 0.f) {
      // exact tie on an occupied column: leave row i free for SAP
      if (lane == 0) u[i] = c2;
      continue;
    }
#pragma unroll
    for (int w = 0; w < 5; ++w) if (lane + 64 * w == j1) v[w] -= delta;
    if (lane == 0) {
      u[i] = c2;
      p[j1] = i;
      rowUsedA[i] = 1;
      if (i1 >= 0) { rowUsedA[i1] = 0; queue[t] = i1; qmisc[1] = t + 1; }
    }
  }
  __syncthreads();

  // ---- collect free rows once (SAP never frees an assigned row) ----
  int nfree;
  {
    int r0 = rowUsedA[lane];
    int r1 = (lane < NM - 64) ? rowUsedA[lane + 64] : 1;
    unsigned long long m0 = __ballot(r0 == 0);
    if (!r0) flist[__popcll(m0 & ((1ull << lane) - 1ull))] = lane;
    int base = (int)__popcll(m0);
    unsigned long long m1 = __ballot(r1 == 0);
    if (!r1) flist[base + (int)__popcll(m1 & ((1ull << lane) - 1ull))] = lane + 64;
    nfree = base + (int)__popcll(m1);
  }
  __syncthreads();

  // register mirrors of p[] and u[] (valid while frozen within a SAP phase)
  int pr0, pr1, pr2, pr3, pr4;
  float ur0, ur1;
  pr0 = p[lane]; pr1 = p[lane + 64]; pr2 = p[lane + 128];
  pr3 = p[lane + 192]; pr4 = p[lane + 256];
  ur0 = u[lane];
  ur1 = (lane < NM - 64) ? u[lane + 64] : 0.f;

  // ---- shortest augmenting path (Dijkstra form) for leftover free rows ----
  for (int fi = 0; fi < nfree; ++fi) {
    int i = flist[fi];
    float dv[5]; int usedR[5];
#pragma unroll
    for (int w = 0; w < 5; ++w) {
      int j = lane + 64 * w;
      dv[w] = INF;
      usedR[w] = (j >= NQ) ? 1 : 0;
      way[j] = -1;
    }
    float S = 0.f;
    int nr = i, j0 = -1;
    while (true) {
      float urow;
      {
        int bits = (nr < 64)
            ? __builtin_amdgcn_readlane(__float_as_int(ur0), nr & 63)
            : __builtin_amdgcn_readlane(__float_as_int(ur1), nr & 63);
        urow = __int_as_float(bits);
      }
      int base = nr * CTP;
      float c0 = cost[base + lane];
      float c1 = cost[base + lane + 64];
      float c2_ = cost[base + lane + 128];
      float c3 = cost[base + lane + 192];
      float c4 = cost[base + lane + 256];   // j>=300 lanes: discarded (usedR)
      float cr[5] = {c0, c1, c2_, c3, c4};
      float cmin = INF;
#pragma unroll
      for (int w = 0; w < 5; ++w) {
        if (!usedR[w]) {
          float cand = S + cr[w] - urow - v[w];
          if (cand < dv[w]) { dv[w] = cand; way[lane + 64 * w] = j0; }
          cmin = fminf(cmin, dv[w]);
        }
      }
      float m = wave_fmin_bcast(cmin);
      int j1 = -1;
#pragma unroll
      for (int w = 0; w < 5; ++w) {
        unsigned long long mk = __ballot(!usedR[w] && dv[w] == m);
        if (j1 < 0 && mk) j1 = (int)__builtin_ctzll(mk) + 64 * w;
      }
      S = m;
#pragma unroll
      for (int w = 0; w < 5; ++w) if (lane + 64 * w == j1) usedR[w] = 1;
      j0 = j1;
      // p[j1] via readlane from mirror (uniform j1; p frozen in-phase)
      int nr2;
      {
        int sl = j1 >> 6, ln = j1 & 63;
        if (sl == 0)      nr2 = __builtin_amdgcn_readlane(pr0, ln);
        else if (sl == 1) nr2 = __builtin_amdgcn_readlane(pr1, ln);
        else if (sl == 2) nr2 = __builtin_amdgcn_readlane(pr2, ln);
        else if (sl == 3) nr2 = __builtin_amdgcn_readlane(pr3, ln);
        else              nr2 = __builtin_amdgcn_readlane(pr4, ln);
      }
      if (nr2 < 0) break;
      nr = nr2;
    }
    // phase-end dual updates (mirror pr* is pre-augmentation p — required)
#pragma unroll
    for (int w = 0; w < 5; ++w) {
      int j = lane + 64 * w;
      if (j < NQ && usedR[w]) {
        float amt = S - dv[w];            // = sum of deltas since j joined
        v[w] -= amt;
        int pj = (w == 0) ? pr0 : (w == 1) ? pr1 : (w == 2) ? pr2
               : (w == 3) ? pr3 : pr4;
        if (pj >= 0) u[pj] += amt;        // distinct rows across lanes
      }
    }
    if (lane == 0) u[i] += S;
    __syncthreads();
    if (lane == 0) {                      // backtrack augmenting path
      int j = j0;
      while (j != -1) {
        int jp = way[j];
        p[j] = (jp != -1) ? p[jp] : i;
        j = jp;
      }
    }
    __syncthreads();
    // refresh mirrors (p rewired by backtrack, u updated above)
    pr0 = p[lane]; pr1 = p[lane + 64]; pr2 = p[lane + 128];
    pr3 = p[lane + 192]; pr4 = p[lane + 256];
    ur0 = u[lane];
    ur1 = (lane < NM - 64) ? u[lane + 64] : 0.f;
  }

  // ---- parallel emit: sorted (pred, gt) pairs via ballot prefix ----
  {
    float* po = out + NB * NQ * NM + b * NM;
    float* go = out + NB * NQ * NM + NB * NM + b * NM;
    int base = 0;
    int prw[5] = {pr0, pr1, pr2, pr3, pr4};
#pragma unroll
    for (int w = 0; w < 5; ++w) {
      int j = lane + 64 * w;
      int pj = (j < NQ) ? prw[w] : -1;
      unsigned long long mask = __ballot(pj >= 0);
      if (pj >= 0) {
        int pos = base + (int)__popcll(mask & ((1ull << lane) - 1ull));
        po[pos] = (float)j;
        go[pos] = (float)pj;
      }
      base += (int)__popcll(mask);
    }
  }
}

// R9: hipFuncSetAttribute hoisted OUT of kernel_launch (suspected graph-
// capture breaker -> slow-path launches). Runs once at .so load; lazy guard
// as fallback. Only marked done on success.
static bool g_attr_done = false;
static void ensure_attr() {
  if (!g_attr_done) {
    if (hipFuncSetAttribute(reinterpret_cast<const void*>(hungarian_kernel),
                            hipFuncAttributeMaxDynamicSharedMemorySize,
                            127472) == hipSuccess)
      g_attr_done = true;
  }
}
__attribute__((constructor)) static void init_attr_ctor() { ensure_attr(); }

extern "C" void kernel_launch(void* const* d_in, const int* in_sizes, int n_in,
                              void* d_out, int out_size, void* d_ws, size_t ws_size,
                              hipStream_t stream) {
  const float* logits = (const float*)d_in[0];
  const float* pboxes = (const float*)d_in[1];
  const float* pmask  = (const float*)d_in[2];
  const int*   labels = (const int*)d_in[3];
  const float* gboxes = (const float*)d_in[4];
  const float* gmask  = (const float*)d_in[5];
  float* out = (float*)d_out;
  char* ws = (char*)d_ws;

  // ws layout (bytes)
  unsigned short* gmb  = (unsigned short*)(ws + 0);          //  26,214,400
  float* dotv  = (float*)(ws + 26214400);                    //     960,000
  float* psum  = (float*)(ws + 27174400);                    //       9,600  (contiguous after dotv)
  float* gsum  = (float*)(ws + 27184000);                    //       3,200
  float* probs = (float*)(ws + 27187200);                    //     777,600
  float* ct    = (float*)(ws + 27964800);                    //     972,800

  ensure_attr();   // no-op after first success

  // 4 dispatches total (was 6 + memset)
  hipLaunchKernelGGL(prep2_kernel, dim3(NB * NM + 600 + 60), dim3(256), 0, stream,
                     gmask, gmb, gsum, logits, probs, dotv);
  hipLaunchKernelGGL(dot_kernel, dim3(19, NB * NKC), dim3(64), 0, stream,
                     pmask, gmb, dotv, psum);
  hipLaunchKernelGGL(combine_kernel, dim3((NB * NQ * NM + 255) / 256), dim3(256), 0, stream,
                     dotv, psum, gsum, probs, labels, pboxes, gboxes, out, ct);
  hipLaunchKernelGGL(hungarian_kernel, dim3(NB), dim3(64), 127472, stream, ct, out);
}